// Round 1
// baseline (395.567 us; speedup 1.0000x reference)
//
#include <hip/hip_runtime.h>
#include <hip/hip_bf16.h>

// Problem constants
#define B_ 16
#define T_ 2048
#define D_ 256
#define QK_ 64

// ---------------------------------------------------------------------------
// Kernel 1: q/k2 projections.
//   qT[b][e][t]  = bq[e] + x[b,t,:]·Wq[e,:]
//   k2T[b][e][t] = (bk[e] + x[b,t,:]·Wk[e,:]) * 0.125 * (1+clip(sl)^2)
// Stored TRANSPOSED ([e][t]) so the score kernels can load LDS tiles with
// coalesced float4 and no on-chip transpose.
// block = 128 threads (64 q-threads + 64 k-threads), 16 t-rows per block.
// ---------------------------------------------------------------------------
__global__ __launch_bounds__(128) void proj_kernel(
    const float* __restrict__ x, const float* __restrict__ sl,
    const float* __restrict__ Wq, const float* __restrict__ bq,
    const float* __restrict__ Wk, const float* __restrict__ bk,
    float* __restrict__ qT, float* __restrict__ k2T)
{
    __shared__ __align__(16) float xs[16][D_];
    __shared__ float ksc[16];
    const int blk = blockIdx.x;
    const int b   = blk >> 7;            // / (T/16 = 128)
    const int t0  = (blk & 127) << 4;    // *16
    const int tid = threadIdx.x;

    // stage 16 x rows (4096 floats = 1024 float4; 8 per thread), coalesced
    {
        const float4* x4 = (const float4*)(x + ((size_t)b * T_ + t0) * D_);
        float4* xs4 = (float4*)(&xs[0][0]);
        #pragma unroll
        for (int i = 0; i < 8; ++i) xs4[i * 128 + tid] = x4[i * 128 + tid];
    }
    if (tid < 16) {
        float s = sl[(size_t)b * T_ + t0 + tid];
        s = fminf(fmaxf(s, 0.f), 1.f);
        ksc[tid] = 0.125f * (1.f + s * s);   // scale * (1+sl^2)
    }
    __syncthreads();

    const int  e   = tid & 63;
    const bool isq = tid < 64;
    const float4* Wr = (const float4*)((isq ? Wq : Wk) + (size_t)e * D_);

    float acc[16];
    #pragma unroll
    for (int r = 0; r < 16; ++r) acc[r] = 0.f;

    for (int d0 = 0; d0 < D_ / 4; ++d0) {
        const float4 w4 = Wr[d0];
        #pragma unroll
        for (int r = 0; r < 16; ++r) {
            const float4 xv = *(const float4*)(&xs[r][d0 * 4]);  // broadcast read
            acc[r] += w4.x * xv.x + w4.y * xv.y + w4.z * xv.z + w4.w * xv.w;
        }
    }

    if (isq) {
        const float bias = bq[e];
        float4* dst = (float4*)(qT + ((size_t)b * QK_ + e) * T_ + t0);
        #pragma unroll
        for (int j = 0; j < 4; ++j) {
            float4 o;
            o.x = acc[4*j+0] + bias; o.y = acc[4*j+1] + bias;
            o.z = acc[4*j+2] + bias; o.w = acc[4*j+3] + bias;
            dst[j] = o;
        }
    } else {
        const float bias = bk[e];
        float4* dst = (float4*)(k2T + ((size_t)b * QK_ + e) * T_ + t0);
        #pragma unroll
        for (int j = 0; j < 4; ++j) {
            float4 o;
            o.x = (acc[4*j+0] + bias) * ksc[4*j+0];
            o.y = (acc[4*j+1] + bias) * ksc[4*j+1];
            o.z = (acc[4*j+2] + bias) * ksc[4*j+2];
            o.w = (acc[4*j+3] + bias) * ksc[4*j+3];
            dst[j] = o;
        }
    }
}

// ---------------------------------------------------------------------------
// Kernel 2 (Z pass): rZ[b][t] = 1 / sum_s( mask[s] * exp(q[t]·k2[s]) )
// Block owns a 128-row t-tile, loops over all s in 128-col tiles.
// 256 threads as 16(ty: rows) x 16(tx: cols), 8x8 micro-tile each.
// K-dim split in halves so static LDS stays <= 64 KB (qs full, ks half).
// ---------------------------------------------------------------------------
__global__ __launch_bounds__(256) void zkernel(
    const float* __restrict__ qT, const float* __restrict__ k2T,
    const int* __restrict__ mask, float* __restrict__ rZ)
{
    __shared__ __align__(16) float qs[QK_][128];   // 32 KB, loaded once
    __shared__ __align__(16) float ks[32][128];    // 16 KB, per (tile,khalf)
    __shared__ float mv[128];
    const int b   = blockIdx.y;
    const int t0  = blockIdx.x * 128;
    const int tid = threadIdx.x;
    const int ty  = tid >> 4, tx = tid & 15;

    const float* qb = qT  + (size_t)b * QK_ * T_;
    const float* kb = k2T + (size_t)b * QK_ * T_;

    {   // load q tile [64][128]: 2048 float4, 8 per thread, coalesced rows
        float4* d4 = (float4*)(&qs[0][0]);
        #pragma unroll
        for (int i = 0; i < 8; ++i) {
            const int f = i * 256 + tid;
            const int e = f >> 5, p = (f & 31) << 2;
            d4[f] = *(const float4*)(qb + (size_t)e * T_ + t0 + p);
        }
    }

    float zacc[8];
    #pragma unroll
    for (int r = 0; r < 8; ++r) zacc[r] = 0.f;

    for (int s0 = 0; s0 < T_; s0 += 128) {
        float sc[8][8];
        #pragma unroll
        for (int r = 0; r < 8; ++r)
            #pragma unroll
            for (int c = 0; c < 8; ++c) sc[r][c] = 0.f;

        #pragma unroll
        for (int kh = 0; kh < 2; ++kh) {
            __syncthreads();   // previous readers of ks/mv done
            {   // load k half-tile [32][128]: 1024 float4, 4 per thread
                float4* d4 = (float4*)(&ks[0][0]);
                #pragma unroll
                for (int i = 0; i < 4; ++i) {
                    const int f = i * 256 + tid;
                    const int e = f >> 5, p = (f & 31) << 2;
                    d4[f] = *(const float4*)(kb + (size_t)(kh * 32 + e) * T_ + s0 + p);
                }
            }
            if (kh == 0 && tid < 128)
                mv[tid] = mask[(size_t)b * T_ + s0 + tid] ? 1.f : 0.f;
            __syncthreads();

            #pragma unroll
            for (int kk = 0; kk < 32; ++kk) {
                float a[8], bb[8];
                *(float4*)&a[0]  = *(const float4*)(&qs[kh * 32 + kk][ty * 8]);
                *(float4*)&a[4]  = *(const float4*)(&qs[kh * 32 + kk][ty * 8 + 4]);
                *(float4*)&bb[0] = *(const float4*)(&ks[kk][tx * 8]);
                *(float4*)&bb[4] = *(const float4*)(&ks[kk][tx * 8 + 4]);
                #pragma unroll
                for (int r = 0; r < 8; ++r)
                    #pragma unroll
                    for (int c = 0; c < 8; ++c) sc[r][c] += a[r] * bb[c];
            }
        }
        // scores bounded (|s| <~ 13) -> exp safe without max subtraction
        #pragma unroll
        for (int c = 0; c < 8; ++c) {
            const float m = mv[tx * 8 + c];
            #pragma unroll
            for (int r = 0; r < 8; ++r) zacc[r] += m * __expf(sc[r][c]);
        }
    }

    // reduce across the 16 tx threads sharing each row (all intra-wave)
    #pragma unroll
    for (int off = 1; off < 16; off <<= 1)
        #pragma unroll
        for (int r = 0; r < 8; ++r) zacc[r] += __shfl_xor(zacc[r], off);

    if (tx == 0) {
        #pragma unroll
        for (int r = 0; r < 8; ++r)
            rZ[(size_t)b * T_ + t0 + ty * 8 + r] = 1.f / zacc[r];
    }
}

// ---------------------------------------------------------------------------
// Kernel 3 (W pass): w[b][s] = mask[s]/T * sum_t exp(q[t]·k2[s]) * rZ[t]
// Block owns a 128-col s-tile (ks resident), loops over t-tiles.
// Column partial sums stay in registers, one LDS reduction at the end.
// ---------------------------------------------------------------------------
__global__ __launch_bounds__(256) void wkernel(
    const float* __restrict__ qT, const float* __restrict__ k2T,
    const int* __restrict__ mask, const float* __restrict__ rZ,
    float* __restrict__ w)
{
    __shared__ __align__(16) float ks[QK_][128];   // 32 KB, loaded once
    __shared__ __align__(16) float qs[32][128];    // 16 KB, per (tile,khalf)
    __shared__ float rzl[128];
    const int b   = blockIdx.y;
    const int s0  = blockIdx.x * 128;
    const int tid = threadIdx.x;
    const int ty  = tid >> 4, tx = tid & 15;

    const float* qb = qT  + (size_t)b * QK_ * T_;
    const float* kb = k2T + (size_t)b * QK_ * T_;

    {   // load k tile [64][128] once
        float4* d4 = (float4*)(&ks[0][0]);
        #pragma unroll
        for (int i = 0; i < 8; ++i) {
            const int f = i * 256 + tid;
            const int e = f >> 5, p = (f & 31) << 2;
            d4[f] = *(const float4*)(kb + (size_t)e * T_ + s0 + p);
        }
    }

    float wacc[8];
    #pragma unroll
    for (int c = 0; c < 8; ++c) wacc[c] = 0.f;

    for (int t0 = 0; t0 < T_; t0 += 128) {
        float sc[8][8];
        #pragma unroll
        for (int r = 0; r < 8; ++r)
            #pragma unroll
            for (int c = 0; c < 8; ++c) sc[r][c] = 0.f;

        #pragma unroll
        for (int kh = 0; kh < 2; ++kh) {
            __syncthreads();
            {   // load q half-tile [32][128]
                float4* d4 = (float4*)(&qs[0][0]);
                #pragma unroll
                for (int i = 0; i < 4; ++i) {
                    const int f = i * 256 + tid;
                    const int e = f >> 5, p = (f & 31) << 2;
                    d4[f] = *(const float4*)(qb + (size_t)(kh * 32 + e) * T_ + t0 + p);
                }
            }
            if (kh == 0 && tid < 128)
                rzl[tid] = rZ[(size_t)b * T_ + t0 + tid];
            __syncthreads();

            #pragma unroll
            for (int kk = 0; kk < 32; ++kk) {
                float a[8], bb[8];
                *(float4*)&a[0]  = *(const float4*)(&qs[kk][ty * 8]);
                *(float4*)&a[4]  = *(const float4*)(&qs[kk][ty * 8 + 4]);
                *(float4*)&bb[0] = *(const float4*)(&ks[kh * 32 + kk][tx * 8]);
                *(float4*)&bb[4] = *(const float4*)(&ks[kh * 32 + kk][tx * 8 + 4]);
                #pragma unroll
                for (int r = 0; r < 8; ++r)
                    #pragma unroll
                    for (int c = 0; c < 8; ++c) sc[r][c] += a[r] * bb[c];
            }
        }
        #pragma unroll
        for (int r = 0; r < 8; ++r) {
            const float rz = rzl[ty * 8 + r];
            #pragma unroll
            for (int c = 0; c < 8; ++c) wacc[c] += __expf(sc[r][c]) * rz;
        }
    }

    // deterministic cross-ty reduction via LDS (reuse qs: need 16*128 floats)
    __syncthreads();
    float* wred = &qs[0][0];
    #pragma unroll
    for (int c = 0; c < 8; ++c) wred[ty * 128 + tx * 8 + c] = wacc[c];
    __syncthreads();
    if (tid < 128) {
        float s = 0.f;
        #pragma unroll
        for (int j = 0; j < 16; ++j) s += wred[j * 128 + tid];
        const float m = mask[(size_t)b * T_ + s0 + tid] ? (1.f / (float)T_) : 0.f;
        w[(size_t)b * T_ + s0 + tid] = s * m;
    }
}

// ---------------------------------------------------------------------------
// Kernel 4: ypart[b][ch][d] = sum_{s in chunk ch} w[b,s] * x[b,s,d]
// grid (16 chunks, B), 256 threads = one d-column each; coalesced x reads.
// ---------------------------------------------------------------------------
__global__ __launch_bounds__(256) void ykernel(
    const float* __restrict__ x, const float* __restrict__ w,
    float* __restrict__ ypart)
{
    const int b  = blockIdx.y;
    const int ch = blockIdx.x;
    const int d  = threadIdx.x;
    const float* xb = x + ((size_t)b * T_ + ch * 128) * D_;
    const float* wb = w + (size_t)b * T_ + ch * 128;
    float acc = 0.f;
    #pragma unroll 4
    for (int s = 0; s < 128; ++s) acc += wb[s] * xb[(size_t)s * D_ + d];
    ypart[((size_t)b * 16 + ch) * D_ + d] = acc;
}

// ---------------------------------------------------------------------------
// Kernel 5: out[b][e] = sum_d y[b,d]*Wv[e,d] + bv[e]*sum_s w[b,s]
// One block per batch.
// ---------------------------------------------------------------------------
__global__ __launch_bounds__(256) void outkernel(
    const float* __restrict__ ypart, const float* __restrict__ w,
    const float* __restrict__ Wv, const float* __restrict__ bv,
    float* __restrict__ out)
{
    __shared__ __align__(16) float ys[D_];
    __shared__ float swl[4];
    const int b   = blockIdx.x;
    const int tid = threadIdx.x;

    float yv = 0.f;
    #pragma unroll
    for (int ch = 0; ch < 16; ++ch) yv += ypart[((size_t)b * 16 + ch) * D_ + tid];
    ys[tid] = yv;

    float s = 0.f;
    #pragma unroll
    for (int i = 0; i < 8; ++i) s += w[(size_t)b * T_ + i * 256 + tid];
    #pragma unroll
    for (int off = 32; off > 0; off >>= 1) s += __shfl_xor(s, off);
    if ((tid & 63) == 0) swl[tid >> 6] = s;
    __syncthreads();

    const float sw = swl[0] + swl[1] + swl[2] + swl[3];
    const float4* wv4 = (const float4*)(Wv + (size_t)tid * D_);
    const float4* ys4 = (const float4*)ys;
    float o = 0.f;
    for (int i = 0; i < D_ / 4; ++i) {
        const float4 a = wv4[i];
        const float4 y = ys4[i];
        o += a.x * y.x + a.y * y.y + a.z * y.z + a.w * y.w;
    }
    out[(size_t)b * D_ + tid] = o + bv[tid] * sw;
}

// ---------------------------------------------------------------------------
extern "C" void kernel_launch(void* const* d_in, const int* in_sizes, int n_in,
                              void* d_out, int out_size, void* d_ws, size_t ws_size,
                              hipStream_t stream)
{
    const float* x    = (const float*)d_in[0];
    const float* sl   = (const float*)d_in[1];
    const int*   mask = (const int*)d_in[2];
    const float* Wq   = (const float*)d_in[3];
    const float* bq   = (const float*)d_in[4];
    const float* Wk   = (const float*)d_in[5];
    const float* bk   = (const float*)d_in[6];
    const float* Wv   = (const float*)d_in[7];
    const float* bv   = (const float*)d_in[8];
    float* out = (float*)d_out;

    // workspace layout (floats): 17.3 MB total
    float* ws  = (float*)d_ws;
    float* qT  = ws;                         // B*QK*T = 2097152
    float* k2T = qT + (size_t)B_ * QK_ * T_; // 2097152
    float* rZ  = k2T + (size_t)B_ * QK_ * T_;// B*T = 32768
    float* w   = rZ + (size_t)B_ * T_;       // 32768
    float* yp  = w + (size_t)B_ * T_;        // B*16*D = 65536

    proj_kernel<<<dim3(B_ * T_ / 16), 128, 0, stream>>>(x, sl, Wq, bq, Wk, bk, qT, k2T);
    zkernel   <<<dim3(T_ / 128, B_), 256, 0, stream>>>(qT, k2T, mask, rZ);
    wkernel   <<<dim3(T_ / 128, B_), 256, 0, stream>>>(qT, k2T, mask, rZ, w);
    ykernel   <<<dim3(16, B_), 256, 0, stream>>>(x, w, yp);
    outkernel <<<dim3(B_), 256, 0, stream>>>(yp, w, Wv, bv, out);
}

// Round 2
// 160.423 us; speedup vs baseline: 2.4658x; 2.4658x over previous
//
#include <hip/hip_runtime.h>
#include <hip/hip_bf16.h>
#include <stdint.h>

// Problem constants
#define B_ 16
#define T_ 2048
#define D_ 256
#define QK_ 64
#define LOG2E 1.44269504088896340736f

typedef _Float16 f16;
typedef _Float16 f16x8 __attribute__((ext_vector_type(8)));
typedef float f32x16 __attribute__((ext_vector_type(16)));

// async global->LDS, 16B per lane. LDS dest = wave-uniform base + lane*16 (HW).
__device__ __forceinline__ void gload_lds16(const void* g, void* l) {
    __builtin_amdgcn_global_load_lds(
        (const __attribute__((address_space(1))) uint32_t*)g,
        (__attribute__((address_space(3))) uint32_t*)l, 16, 0, 0);
}

// ---------------------------------------------------------------------------
// Kernel 1: projections -> fp16, row-major [t][e].
//   qh[b][t][e]  = bq[e] + x[b,t,:]·Wq[e,:]
//   k2h[b][t][e] = (bk[e] + x[b,t,:]·Wk[e,:]) * 0.125*(1+clip(sl)^2)*log2e
// (log2e folded so score GEMM output is in log2 space -> native v_exp_f32)
// block = 128 threads (wave0: 64 q cols, wave1: 64 k cols), 16 t-rows/block.
// fp16 outputs written coalesced via LDS transpose.
// ---------------------------------------------------------------------------
__global__ __launch_bounds__(128) void proj_kernel(
    const float* __restrict__ x, const float* __restrict__ sl,
    const float* __restrict__ Wq, const float* __restrict__ bq,
    const float* __restrict__ Wk, const float* __restrict__ bk,
    f16* __restrict__ qh, f16* __restrict__ k2h)
{
    __shared__ __align__(16) float xs[16][D_];
    __shared__ float ksc[16];
    __shared__ __align__(16) f16 hout[16][128];
    const int blk = blockIdx.x;
    const int b   = blk >> 7;            // / (T/16 = 128)
    const int t0  = (blk & 127) << 4;    // *16
    const int tid = threadIdx.x;

    {   // stage 16 x rows (4096 floats = 1024 float4; 8/thread), coalesced
        const float4* x4 = (const float4*)(x + ((size_t)b * T_ + t0) * D_);
        float4* xs4 = (float4*)(&xs[0][0]);
        #pragma unroll
        for (int i = 0; i < 8; ++i) xs4[i * 128 + tid] = x4[i * 128 + tid];
    }
    if (tid < 16) {
        float s = sl[(size_t)b * T_ + t0 + tid];
        s = fminf(fmaxf(s, 0.f), 1.f);
        ksc[tid] = 0.125f * (1.f + s * s) * LOG2E;
    }
    __syncthreads();

    const int  e   = tid & 63;
    const bool isq = tid < 64;
    const float4* Wr = (const float4*)((isq ? Wq : Wk) + (size_t)e * D_);

    float acc[16];
    #pragma unroll
    for (int r = 0; r < 16; ++r) acc[r] = 0.f;

    for (int d0 = 0; d0 < D_ / 4; ++d0) {
        const float4 w4 = Wr[d0];
        #pragma unroll
        for (int r = 0; r < 16; ++r) {
            const float4 xv = *(const float4*)(&xs[r][d0 * 4]);  // broadcast
            acc[r] += w4.x * xv.x + w4.y * xv.y + w4.z * xv.z + w4.w * xv.w;
        }
    }

    if (isq) {
        const float bias = bq[e];
        #pragma unroll
        for (int r = 0; r < 16; ++r) hout[r][e] = (f16)(acc[r] + bias);
    } else {
        const float bias = bk[e];
        #pragma unroll
        for (int r = 0; r < 16; ++r) hout[r][64 + e] = (f16)((acc[r] + bias) * ksc[r]);
    }
    __syncthreads();

    // coalesced fp16 stores: thread i -> row i>>3, 8-half chunk (i&7)
    const int r  = tid >> 3;
    const int c0 = (tid & 7) * 8;
    *(float4*)(qh  + ((size_t)b * T_ + t0 + r) * QK_ + c0) = *(const float4*)(&hout[r][c0]);
    *(float4*)(k2h + ((size_t)b * T_ + t0 + r) * QK_ + c0) = *(const float4*)(&hout[r][64 + c0]);
}

// ---------------------------------------------------------------------------
// MFMA fragment layout assumptions (gfx950 v_mfma_f32_32x32x16_f16):
//   A[row][k]: lane l holds 8 contiguous k: row = l&31, k = (l>>5)*8 + j
//   B[k][col]: lane l holds                col = l&31, k = (l>>5)*8 + j
//   C/D      : col = l&31, row = (reg&3) + 8*(reg>>2) + 4*(l>>5)   [m74/m101]
// LDS tile [128 rows][64 e] fp16, XOR-swizzled: 16B chunk j stored at j^(row&7).
// Stage via global_load_lds with pre-swizzled SOURCE (linear LDS dest).
// ---------------------------------------------------------------------------

// Kernel 2 (Z pass): lrz2[b][t] = -log2( sum_s 2^(S2[t,s] + maskbias[s]) )
// S2 = q·k2 (already in log2 units). Block: 128 t-rows, 4 waves x 32 rows,
// streams k2 in 128-row tiles, double-buffered.
__global__ __launch_bounds__(256) void zkernel(
    const f16* __restrict__ qh, const f16* __restrict__ k2h,
    const int* __restrict__ mask, float* __restrict__ lrz2)
{
    __shared__ __align__(16) f16 kt[2][128 * QK_];   // 2 x 16 KB
    __shared__ float mv[2][128];
    const int b = blockIdx.y, t0 = blockIdx.x * 128;
    const int tid = threadIdx.x;
    const int wv = tid >> 6, l = tid & 63, lo = l & 31, hi = l >> 5;

    // A fragments: this wave's 32 q rows, kept in registers
    const f16* qrow = qh + (size_t)(b * T_ + t0 + wv * 32 + lo) * QK_;
    f16x8 a[4];
    #pragma unroll
    for (int kc = 0; kc < 4; ++kc)
        a[kc] = *(const f16x8*)(qrow + kc * 16 + hi * 8);

    float zp[16];
    #pragma unroll
    for (int i = 0; i < 16; ++i) zp[i] = 0.f;

    auto stage = [&](int s0, int buf) {
        const char* src = (const char*)(k2h + (size_t)(b * T_ + s0) * QK_);
        #pragma unroll
        for (int i = 0; i < 4; ++i) {
            const int o = wv * 4096 + i * 1024 + l * 16;   // byte offset in tile
            const int r = o >> 7, jc = (o >> 4) & 7;
            gload_lds16(src + r * 128 + ((jc ^ (r & 7)) << 4),
                        (char*)kt[buf] + wv * 4096 + i * 1024);
        }
        if (tid < 128) mv[buf][tid] = mask[b * T_ + s0 + tid] ? 0.f : -1e9f;
    };

    stage(0, 0);
    __syncthreads();
    int cur = 0;
    for (int it = 0; it < T_ / 128; ++it) {
        if (it + 1 < T_ / 128) stage((it + 1) * 128, cur ^ 1);
        const f16* ktc = kt[cur];
        #pragma unroll
        for (int cg = 0; cg < 4; ++cg) {
            const int srow = cg * 32 + lo;
            const float mb = mv[cur][srow];     // mask bias per column s
            f32x16 c;
            #pragma unroll
            for (int i = 0; i < 16; ++i) c[i] = mb;
            #pragma unroll
            for (int kc = 0; kc < 4; ++kc) {
                const int jcc = (kc * 2 + hi) ^ (srow & 7);
                const f16x8 bf = *(const f16x8*)((const char*)ktc + srow * 128 + (jcc << 4));
                c = __builtin_amdgcn_mfma_f32_32x32x16_f16(a[kc], bf, c, 0, 0, 0);
            }
            #pragma unroll
            for (int i = 0; i < 16; ++i) zp[i] += exp2f(c[i]);
        }
        __syncthreads();   // drains vmcnt (next tile staged) + protects bufs
        cur ^= 1;
    }

    #pragma unroll
    for (int off = 1; off <= 16; off <<= 1)
        #pragma unroll
        for (int i = 0; i < 16; ++i) zp[i] += __shfl_xor(zp[i], off);

    if (lo == 0) {
        #pragma unroll
        for (int i = 0; i < 16; ++i) {
            const int row = (i & 3) + 8 * (i >> 2) + 4 * hi;
            lrz2[b * T_ + t0 + wv * 32 + row] = -log2f(zp[i]);
        }
    }
}

// Kernel 3 (W pass): w[s] = (mask[s]/T) * sum_t 2^(S2[t,s] + lrz2[t])
// Mirror of Z: A = k2 rows (block's 128 s), streams q tiles; lrz2 folded
// into accumulator init (per-column bias).
__global__ __launch_bounds__(256) void wkernel(
    const f16* __restrict__ qh, const f16* __restrict__ k2h,
    const int* __restrict__ mask, const float* __restrict__ lrz2,
    float* __restrict__ wgt)
{
    __shared__ __align__(16) f16 qt[2][128 * QK_];
    __shared__ float lz[2][128];
    const int b = blockIdx.y, s0b = blockIdx.x * 128;
    const int tid = threadIdx.x;
    const int wv = tid >> 6, l = tid & 63, lo = l & 31, hi = l >> 5;

    const f16* krow = k2h + (size_t)(b * T_ + s0b + wv * 32 + lo) * QK_;
    f16x8 a[4];
    #pragma unroll
    for (int kc = 0; kc < 4; ++kc)
        a[kc] = *(const f16x8*)(krow + kc * 16 + hi * 8);

    float wp[16];
    #pragma unroll
    for (int i = 0; i < 16; ++i) wp[i] = 0.f;

    auto stage = [&](int t0, int buf) {
        const char* src = (const char*)(qh + (size_t)(b * T_ + t0) * QK_);
        #pragma unroll
        for (int i = 0; i < 4; ++i) {
            const int o = wv * 4096 + i * 1024 + l * 16;
            const int r = o >> 7, jc = (o >> 4) & 7;
            gload_lds16(src + r * 128 + ((jc ^ (r & 7)) << 4),
                        (char*)qt[buf] + wv * 4096 + i * 1024);
        }
        if (tid < 128) lz[buf][tid] = lrz2[b * T_ + t0 + tid];
    };

    stage(0, 0);
    __syncthreads();
    int cur = 0;
    for (int it = 0; it < T_ / 128; ++it) {
        if (it + 1 < T_ / 128) stage((it + 1) * 128, cur ^ 1);
        const f16* qtc = qt[cur];
        #pragma unroll
        for (int cg = 0; cg < 4; ++cg) {
            const int trow = cg * 32 + lo;
            const float bias = lz[cur][trow];   // lrz2 per column t
            f32x16 c;
            #pragma unroll
            for (int i = 0; i < 16; ++i) c[i] = bias;
            #pragma unroll
            for (int kc = 0; kc < 4; ++kc) {
                const int jcc = (kc * 2 + hi) ^ (trow & 7);
                const f16x8 bf = *(const f16x8*)((const char*)qtc + trow * 128 + (jcc << 4));
                c = __builtin_amdgcn_mfma_f32_32x32x16_f16(a[kc], bf, c, 0, 0, 0);
            }
            #pragma unroll
            for (int i = 0; i < 16; ++i) wp[i] += exp2f(c[i]);  // = prob[t][s]
        }
        __syncthreads();
        cur ^= 1;
    }

    #pragma unroll
    for (int off = 1; off <= 16; off <<= 1)
        #pragma unroll
        for (int i = 0; i < 16; ++i) wp[i] += __shfl_xor(wp[i], off);

    if (lo == 0) {
        #pragma unroll
        for (int i = 0; i < 16; ++i) {
            const int row = (i & 3) + 8 * (i >> 2) + 4 * hi;
            const int s = s0b + wv * 32 + row;
            const float m = mask[b * T_ + s] ? (1.f / (float)T_) : 0.f;
            wgt[b * T_ + s] = wp[i] * m;
        }
    }
}

// ---------------------------------------------------------------------------
// Kernel 4: ypart[b][ch][d] = sum_{s in chunk ch} w[b,s] * x[b,s,d]
// ---------------------------------------------------------------------------
__global__ __launch_bounds__(256) void ykernel(
    const float* __restrict__ x, const float* __restrict__ w,
    float* __restrict__ ypart)
{
    const int b  = blockIdx.y;
    const int ch = blockIdx.x;
    const int d  = threadIdx.x;
    const float* xb = x + ((size_t)b * T_ + ch * 128) * D_;
    const float* wb = w + (size_t)b * T_ + ch * 128;
    float acc = 0.f;
    #pragma unroll 4
    for (int s = 0; s < 128; ++s) acc += wb[s] * xb[(size_t)s * D_ + d];
    ypart[((size_t)b * 16 + ch) * D_ + d] = acc;
}

// ---------------------------------------------------------------------------
// Kernel 5: out[b][e] = sum_d y[b,d]*Wv[e,d] + bv[e]*sum_s w[b,s]
// ---------------------------------------------------------------------------
__global__ __launch_bounds__(256) void outkernel(
    const float* __restrict__ ypart, const float* __restrict__ w,
    const float* __restrict__ Wv, const float* __restrict__ bv,
    float* __restrict__ out)
{
    __shared__ __align__(16) float ys[D_];
    __shared__ float swl[4];
    const int b   = blockIdx.x;
    const int tid = threadIdx.x;

    float yv = 0.f;
    #pragma unroll
    for (int ch = 0; ch < 16; ++ch) yv += ypart[((size_t)b * 16 + ch) * D_ + tid];
    ys[tid] = yv;

    float s = 0.f;
    #pragma unroll
    for (int i = 0; i < 8; ++i) s += w[(size_t)b * T_ + i * 256 + tid];
    #pragma unroll
    for (int off = 32; off > 0; off >>= 1) s += __shfl_xor(s, off);
    if ((tid & 63) == 0) swl[tid >> 6] = s;
    __syncthreads();

    const float sw = swl[0] + swl[1] + swl[2] + swl[3];
    const float4* wv4 = (const float4*)(Wv + (size_t)tid * D_);
    const float4* ys4 = (const float4*)ys;
    float o = 0.f;
    for (int i = 0; i < D_ / 4; ++i) {
        const float4 a = wv4[i];
        const float4 y = ys4[i];
        o += a.x * y.x + a.y * y.y + a.z * y.z + a.w * y.w;
    }
    out[(size_t)b * D_ + tid] = o + bv[tid] * sw;
}

// ---------------------------------------------------------------------------
extern "C" void kernel_launch(void* const* d_in, const int* in_sizes, int n_in,
                              void* d_out, int out_size, void* d_ws, size_t ws_size,
                              hipStream_t stream)
{
    const float* x    = (const float*)d_in[0];
    const float* sl   = (const float*)d_in[1];
    const int*   mask = (const int*)d_in[2];
    const float* Wq   = (const float*)d_in[3];
    const float* bq   = (const float*)d_in[4];
    const float* Wk   = (const float*)d_in[5];
    const float* bk   = (const float*)d_in[6];
    const float* Wv   = (const float*)d_in[7];
    const float* bv   = (const float*)d_in[8];
    float* out = (float*)d_out;

    // workspace layout: qh 4MB | k2h 4MB | lrz2 128KB | w 128KB | yp 256KB
    f16*   qh   = (f16*)d_ws;
    f16*   k2h  = qh + (size_t)B_ * T_ * QK_;
    float* lrz2 = (float*)(k2h + (size_t)B_ * T_ * QK_);
    float* w    = lrz2 + (size_t)B_ * T_;
    float* yp   = w + (size_t)B_ * T_;

    proj_kernel<<<dim3(B_ * T_ / 16), 128, 0, stream>>>(x, sl, Wq, bq, Wk, bk, qh, k2h);
    zkernel   <<<dim3(T_ / 128, B_), 256, 0, stream>>>(qh, k2h, mask, lrz2);
    wkernel   <<<dim3(T_ / 128, B_), 256, 0, stream>>>(qh, k2h, mask, lrz2, w);
    ykernel   <<<dim3(16, B_), 256, 0, stream>>>(x, w, yp);
    outkernel <<<dim3(B_), 256, 0, stream>>>(yp, w, Wv, bv, out);
}

// Round 3
// 118.165 us; speedup vs baseline: 3.3476x; 1.3576x over previous
//
#include <hip/hip_runtime.h>
#include <hip/hip_bf16.h>
#include <stdint.h>

// Problem constants
#define B_ 16
#define T_ 2048
#define D_ 256
#define QK_ 64
#define LOG2E 1.44269504088896340736f

typedef _Float16 f16;
typedef _Float16 f16x8 __attribute__((ext_vector_type(8)));
typedef float f32x16 __attribute__((ext_vector_type(16)));

// async global->LDS, 16B per lane. LDS dest = wave-uniform base + lane*16 (HW).
__device__ __forceinline__ void gload_lds16(const void* g, void* l) {
    __builtin_amdgcn_global_load_lds(
        (const __attribute__((address_space(1))) uint32_t*)g,
        (__attribute__((address_space(3))) uint32_t*)l, 16, 0, 0);
}

// ---------------------------------------------------------------------------
// Kernel 0: cast Wq||Wk -> f16 wh[128][256] (row e: e<64 -> Wq[e], else Wk[e-64])
// ---------------------------------------------------------------------------
__global__ __launch_bounds__(256) void wconv_kernel(
    const float* __restrict__ Wq, const float* __restrict__ Wk,
    f16* __restrict__ wh)
{
    const int i = blockIdx.x * 256 + threadIdx.x;   // 0..32767
    const float v = (i < 64 * 256) ? Wq[i] : Wk[i - 64 * 256];
    wh[i] = (f16)v;
}

// ---------------------------------------------------------------------------
// Kernel 1: MFMA projection.
//   [qh|k2h][b][t][e] from x[b,t,:] (f32->f16) x wh (f16), f32 accum.
//   k2h scaled by 0.125*(1+clip(sl)^2)*log2e (score GEMM then uses exp2).
// Block: 256 thr / 4 waves, 64 t-rows. wave wv: rows (wv&1)*32, cols (wv>>1)*64.
// A staged in LDS [64][256] f16, fully XOR-swizzled (chunk ^= row&31) ->
// conflict-free ds_read_b128. B frags read directly from wh (L2-resident):
// B[k][col] = wh[col][k..k+8] contiguous.
// MFMA 32x32x16_f16 layout (verified R2):
//   A: row=l&31, k=(l>>5)*8+j ; B: col=l&31, k=(l>>5)*8+j
//   C: col=l&31, row=(i&3)+8*(i>>2)+4*(l>>5)
// ---------------------------------------------------------------------------
__global__ __launch_bounds__(256) void proj_mfma(
    const float* __restrict__ x, const float* __restrict__ sl,
    const f16* __restrict__ wh,
    const float* __restrict__ bq, const float* __restrict__ bk,
    f16* __restrict__ qh, f16* __restrict__ k2h)
{
    __shared__ __align__(16) f16 xs[64 * D_];   // 32 KB
    __shared__ float ksc[64];
    const int b = blockIdx.y, t0 = blockIdx.x * 64;
    const int tid = threadIdx.x;
    const int wv = tid >> 6, l = tid & 63, lo = l & 31, hi = l >> 5;

    // stage x tile [64][256] f32->f16, swizzled; 2048 16B-chunks, 8/thread
    #pragma unroll
    for (int i = 0; i < 8; ++i) {
        const int f = i * 256 + tid;
        const int r = f >> 5, j = f & 31;
        const float* src = x + ((size_t)b * T_ + t0 + r) * D_ + j * 8;
        const float4 a0 = *(const float4*)src;
        const float4 a1 = *(const float4*)(src + 4);
        f16x8 h;
        h[0] = (f16)a0.x; h[1] = (f16)a0.y; h[2] = (f16)a0.z; h[3] = (f16)a0.w;
        h[4] = (f16)a1.x; h[5] = (f16)a1.y; h[6] = (f16)a1.z; h[7] = (f16)a1.w;
        *(f16x8*)(xs + r * D_ + ((j ^ (r & 31)) << 3)) = h;
    }
    if (tid < 64) {
        float s = sl[(size_t)b * T_ + t0 + tid];
        s = fminf(fmaxf(s, 0.f), 1.f);
        ksc[tid] = 0.125f * (1.f + s * s) * LOG2E;
    }
    __syncthreads();

    const int r0 = (wv & 1) * 32, c0 = (wv >> 1) * 64;
    f32x16 acc0, acc1;
    #pragma unroll
    for (int i = 0; i < 16; ++i) { acc0[i] = 0.f; acc1[i] = 0.f; }

    const int r = r0 + lo;
    const f16* wrow0 = wh + (size_t)(c0 + lo) * D_ + hi * 8;
    const f16* wrow1 = wh + (size_t)(c0 + 32 + lo) * D_ + hi * 8;
    #pragma unroll
    for (int ks = 0; ks < 16; ++ks) {
        const f16x8 a  = *(const f16x8*)(xs + r * D_ + ((((ks << 1) + hi) ^ (r & 31)) << 3));
        const f16x8 b0 = *(const f16x8*)(wrow0 + ks * 16);
        const f16x8 b1 = *(const f16x8*)(wrow1 + ks * 16);
        acc0 = __builtin_amdgcn_mfma_f32_32x32x16_f16(a, b0, acc0, 0, 0, 0);
        acc1 = __builtin_amdgcn_mfma_f32_32x32x16_f16(a, b1, acc1, 0, 0, 0);
    }

    __syncthreads();                 // all waves done reading xs
    f16* hout = xs;                  // reuse as [64][128]
    {
        const int col0 = c0 + lo, col1 = c0 + 32 + lo;
        const float bias0 = (col0 < 64) ? bq[col0] : bk[col0 - 64];
        const float bias1 = (col1 < 64) ? bq[col1] : bk[col1 - 64];
        #pragma unroll
        for (int i = 0; i < 16; ++i) {
            const int row = r0 + (i & 3) + 8 * (i >> 2) + 4 * hi;
            float v0 = acc0[i] + bias0;
            float v1 = acc1[i] + bias1;
            if (col0 >= 64) v0 *= ksc[row];
            if (col1 >= 64) v1 *= ksc[row];
            hout[row * 128 + col0] = (f16)v0;
            hout[row * 128 + col1] = (f16)v1;
        }
    }
    __syncthreads();
    // coalesced stores: 64 rows x 16 chunks(16B), 4/thread
    #pragma unroll
    for (int i = 0; i < 4; ++i) {
        const int f = i * 256 + tid;
        const int rr = f >> 4, j = f & 15;
        const f16x8 v = *(const f16x8*)(hout + rr * 128 + j * 8);
        if (j < 8) *(f16x8*)(qh  + ((size_t)b * T_ + t0 + rr) * QK_ + j * 8) = v;
        else       *(f16x8*)(k2h + ((size_t)b * T_ + t0 + rr) * QK_ + (j - 8) * 8) = v;
    }
}

// ---------------------------------------------------------------------------
// Kernel 2 (Z pass): lrz2[b][t] = -log2( sum_s 2^(S2[t,s] + maskbias[s]) )
// ---------------------------------------------------------------------------
__global__ __launch_bounds__(256) void zkernel(
    const f16* __restrict__ qh, const f16* __restrict__ k2h,
    const int* __restrict__ mask, float* __restrict__ lrz2)
{
    __shared__ __align__(16) f16 kt[2][128 * QK_];   // 2 x 16 KB
    __shared__ float mv[2][128];
    const int b = blockIdx.y, t0 = blockIdx.x * 128;
    const int tid = threadIdx.x;
    const int wv = tid >> 6, l = tid & 63, lo = l & 31, hi = l >> 5;

    const f16* qrow = qh + (size_t)(b * T_ + t0 + wv * 32 + lo) * QK_;
    f16x8 a[4];
    #pragma unroll
    for (int kc = 0; kc < 4; ++kc)
        a[kc] = *(const f16x8*)(qrow + kc * 16 + hi * 8);

    float zp[16];
    #pragma unroll
    for (int i = 0; i < 16; ++i) zp[i] = 0.f;

    auto stage = [&](int s0, int buf) {
        const char* src = (const char*)(k2h + (size_t)(b * T_ + s0) * QK_);
        #pragma unroll
        for (int i = 0; i < 4; ++i) {
            const int o = wv * 4096 + i * 1024 + l * 16;
            const int r = o >> 7, jc = (o >> 4) & 7;
            gload_lds16(src + r * 128 + ((jc ^ (r & 7)) << 4),
                        (char*)kt[buf] + wv * 4096 + i * 1024);
        }
        if (tid < 128) mv[buf][tid] = mask[b * T_ + s0 + tid] ? 0.f : -1e9f;
    };

    stage(0, 0);
    __syncthreads();
    int cur = 0;
    for (int it = 0; it < T_ / 128; ++it) {
        if (it + 1 < T_ / 128) stage((it + 1) * 128, cur ^ 1);
        const f16* ktc = kt[cur];
        #pragma unroll
        for (int cg = 0; cg < 4; ++cg) {
            const int srow = cg * 32 + lo;
            const float mb = mv[cur][srow];
            f32x16 c;
            #pragma unroll
            for (int i = 0; i < 16; ++i) c[i] = mb;
            #pragma unroll
            for (int kc = 0; kc < 4; ++kc) {
                const int jcc = (kc * 2 + hi) ^ (srow & 7);
                const f16x8 bf = *(const f16x8*)((const char*)ktc + srow * 128 + (jcc << 4));
                c = __builtin_amdgcn_mfma_f32_32x32x16_f16(a[kc], bf, c, 0, 0, 0);
            }
            #pragma unroll
            for (int i = 0; i < 16; ++i) zp[i] += exp2f(c[i]);
        }
        __syncthreads();
        cur ^= 1;
    }

    #pragma unroll
    for (int off = 1; off <= 16; off <<= 1)
        #pragma unroll
        for (int i = 0; i < 16; ++i) zp[i] += __shfl_xor(zp[i], off);

    if (lo == 0) {
        #pragma unroll
        for (int i = 0; i < 16; ++i) {
            const int row = (i & 3) + 8 * (i >> 2) + 4 * hi;
            lrz2[b * T_ + t0 + wv * 32 + row] = -log2f(zp[i]);
        }
    }
}

// ---------------------------------------------------------------------------
// Kernel 3 (W pass): w[s] = (mask[s]/T) * sum_t 2^(S2[t,s] + lrz2[t])
// ---------------------------------------------------------------------------
__global__ __launch_bounds__(256) void wkernel(
    const f16* __restrict__ qh, const f16* __restrict__ k2h,
    const int* __restrict__ mask, const float* __restrict__ lrz2,
    float* __restrict__ wgt)
{
    __shared__ __align__(16) f16 qt[2][128 * QK_];
    __shared__ float lz[2][128];
    const int b = blockIdx.y, s0b = blockIdx.x * 128;
    const int tid = threadIdx.x;
    const int wv = tid >> 6, l = tid & 63, lo = l & 31, hi = l >> 5;

    const f16* krow = k2h + (size_t)(b * T_ + s0b + wv * 32 + lo) * QK_;
    f16x8 a[4];
    #pragma unroll
    for (int kc = 0; kc < 4; ++kc)
        a[kc] = *(const f16x8*)(krow + kc * 16 + hi * 8);

    float wp[16];
    #pragma unroll
    for (int i = 0; i < 16; ++i) wp[i] = 0.f;

    auto stage = [&](int t0, int buf) {
        const char* src = (const char*)(qh + (size_t)(b * T_ + t0) * QK_);
        #pragma unroll
        for (int i = 0; i < 4; ++i) {
            const int o = wv * 4096 + i * 1024 + l * 16;
            const int r = o >> 7, jc = (o >> 4) & 7;
            gload_lds16(src + r * 128 + ((jc ^ (r & 7)) << 4),
                        (char*)qt[buf] + wv * 4096 + i * 1024);
        }
        if (tid < 128) lz[buf][tid] = lrz2[b * T_ + t0 + tid];
    };

    stage(0, 0);
    __syncthreads();
    int cur = 0;
    for (int it = 0; it < T_ / 128; ++it) {
        if (it + 1 < T_ / 128) stage((it + 1) * 128, cur ^ 1);
        const f16* qtc = qt[cur];
        #pragma unroll
        for (int cg = 0; cg < 4; ++cg) {
            const int trow = cg * 32 + lo;
            const float bias = lz[cur][trow];
            f32x16 c;
            #pragma unroll
            for (int i = 0; i < 16; ++i) c[i] = bias;
            #pragma unroll
            for (int kc = 0; kc < 4; ++kc) {
                const int jcc = (kc * 2 + hi) ^ (trow & 7);
                const f16x8 bf = *(const f16x8*)((const char*)qtc + trow * 128 + (jcc << 4));
                c = __builtin_amdgcn_mfma_f32_32x32x16_f16(a[kc], bf, c, 0, 0, 0);
            }
            #pragma unroll
            for (int i = 0; i < 16; ++i) wp[i] += exp2f(c[i]);
        }
        __syncthreads();
        cur ^= 1;
    }

    #pragma unroll
    for (int off = 1; off <= 16; off <<= 1)
        #pragma unroll
        for (int i = 0; i < 16; ++i) wp[i] += __shfl_xor(wp[i], off);

    if (lo == 0) {
        #pragma unroll
        for (int i = 0; i < 16; ++i) {
            const int row = (i & 3) + 8 * (i >> 2) + 4 * hi;
            const int s = s0b + wv * 32 + row;
            const float m = mask[b * T_ + s] ? (1.f / (float)T_) : 0.f;
            wgt[b * T_ + s] = wp[i] * m;
        }
    }
}

// ---------------------------------------------------------------------------
// Kernel 4: ypart[b][ch][d] = sum_{s in 32-row chunk ch} w[b,s] * x[b,s,d]
// 64 chunks -> 1024 blocks (4/CU) for latency hiding.
// ---------------------------------------------------------------------------
__global__ __launch_bounds__(256) void ykernel(
    const float* __restrict__ x, const float* __restrict__ w,
    float* __restrict__ ypart)
{
    const int b  = blockIdx.y;
    const int ch = blockIdx.x;
    const int d  = threadIdx.x;
    const float* xb = x + ((size_t)b * T_ + ch * 32) * D_;
    const float* wb = w + (size_t)b * T_ + ch * 32;
    float acc = 0.f;
    #pragma unroll 8
    for (int s = 0; s < 32; ++s) acc += wb[s] * xb[(size_t)s * D_ + d];
    ypart[((size_t)b * 64 + ch) * D_ + d] = acc;
}

// ---------------------------------------------------------------------------
// Kernel 5: out[b][e] = sum_d y[b,d]*Wv[e,d] + bv[e]*sum_s w[b,s]
// ---------------------------------------------------------------------------
__global__ __launch_bounds__(256) void outkernel(
    const float* __restrict__ ypart, const float* __restrict__ w,
    const float* __restrict__ Wv, const float* __restrict__ bv,
    float* __restrict__ out)
{
    __shared__ __align__(16) float ys[D_];
    __shared__ float swl[4];
    const int b   = blockIdx.x;
    const int tid = threadIdx.x;

    float yv = 0.f;
    #pragma unroll
    for (int ch = 0; ch < 64; ++ch) yv += ypart[((size_t)b * 64 + ch) * D_ + tid];
    ys[tid] = yv;

    float s = 0.f;
    #pragma unroll
    for (int i = 0; i < 8; ++i) s += w[(size_t)b * T_ + i * 256 + tid];
    #pragma unroll
    for (int off = 32; off > 0; off >>= 1) s += __shfl_xor(s, off);
    if ((tid & 63) == 0) swl[tid >> 6] = s;
    __syncthreads();

    const float sw = swl[0] + swl[1] + swl[2] + swl[3];
    const float4* wv4 = (const float4*)(Wv + (size_t)tid * D_);
    const float4* ys4 = (const float4*)ys;
    float o = 0.f;
    for (int i = 0; i < D_ / 4; ++i) {
        const float4 a = wv4[i];
        const float4 y = ys4[i];
        o += a.x * y.x + a.y * y.y + a.z * y.z + a.w * y.w;
    }
    out[(size_t)b * D_ + tid] = o + bv[tid] * sw;
}

// ---------------------------------------------------------------------------
extern "C" void kernel_launch(void* const* d_in, const int* in_sizes, int n_in,
                              void* d_out, int out_size, void* d_ws, size_t ws_size,
                              hipStream_t stream)
{
    const float* x    = (const float*)d_in[0];
    const float* sl   = (const float*)d_in[1];
    const int*   mask = (const int*)d_in[2];
    const float* Wq   = (const float*)d_in[3];
    const float* bq   = (const float*)d_in[4];
    const float* Wk   = (const float*)d_in[5];
    const float* bk   = (const float*)d_in[6];
    const float* Wv   = (const float*)d_in[7];
    const float* bv   = (const float*)d_in[8];
    float* out = (float*)d_out;

    // workspace: qh 4MB | k2h 4MB | wh 64KB | lrz2 128KB | w 128KB | yp 1MB
    f16*   qh   = (f16*)d_ws;
    f16*   k2h  = qh + (size_t)B_ * T_ * QK_;
    f16*   wh   = k2h + (size_t)B_ * T_ * QK_;
    float* lrz2 = (float*)(wh + 128 * D_);
    float* w    = lrz2 + (size_t)B_ * T_;
    float* yp   = w + (size_t)B_ * T_;

    wconv_kernel<<<dim3(128), 256, 0, stream>>>(Wq, Wk, wh);
    proj_mfma  <<<dim3(T_ / 64, B_), 256, 0, stream>>>(x, sl, wh, bq, bk, qh, k2h);
    zkernel    <<<dim3(T_ / 128, B_), 256, 0, stream>>>(qh, k2h, mask, lrz2);
    wkernel    <<<dim3(T_ / 128, B_), 256, 0, stream>>>(qh, k2h, mask, lrz2, w);
    ykernel    <<<dim3(64, B_), 256, 0, stream>>>(x, w, yp);
    outkernel  <<<dim3(B_), 256, 0, stream>>>(yp, w, Wv, bv, out);
}

// Round 4
// 81.309 us; speedup vs baseline: 4.8650x; 1.4533x over previous
//
#include <hip/hip_runtime.h>
#include <hip/hip_bf16.h>
#include <stdint.h>

// Problem constants
#define B_ 16
#define T_ 2048
#define D_ 256
#define QK_ 64
#define LOG2E 1.44269504088896340736f

typedef _Float16 f16;
typedef _Float16 f16x8 __attribute__((ext_vector_type(8)));
typedef float f32x16 __attribute__((ext_vector_type(16)));

// async global->LDS, 16B per lane. LDS dest = wave-uniform base + lane*16 (HW).
__device__ __forceinline__ void gload_lds16(const void* g, void* l) {
    __builtin_amdgcn_global_load_lds(
        (const __attribute__((address_space(1))) uint32_t*)g,
        (__attribute__((address_space(3))) uint32_t*)l, 16, 0, 0);
}

// raw v_exp_f32 / v_log_f32 (base-2); avoids libm denormal-guard sequences
__device__ __forceinline__ float fexp2(float x) {
#if __has_builtin(__builtin_amdgcn_exp2f)
    return __builtin_amdgcn_exp2f(x);
#else
    return exp2f(x);
#endif
}
__device__ __forceinline__ float flog2(float x) {
#if __has_builtin(__builtin_amdgcn_logf)
    return __builtin_amdgcn_logf(x);
#else
    return log2f(x);
#endif
}

// ---------------------------------------------------------------------------
// Kernel 0: cast Wq||Wk -> f16 wh[128][256]
// ---------------------------------------------------------------------------
__global__ __launch_bounds__(256) void wconv_kernel(
    const float* __restrict__ Wq, const float* __restrict__ Wk,
    f16* __restrict__ wh)
{
    const int i = blockIdx.x * 256 + threadIdx.x;   // 0..32767
    const float v = (i < 64 * 256) ? Wq[i] : Wk[i - 64 * 256];
    wh[i] = (f16)v;
}

// ---------------------------------------------------------------------------
// Kernel 1: MFMA projection (unchanged from R3).
//   [qh|k2h][b][t][e]; k2h scaled by 0.125*(1+clip(sl)^2)*log2e.
// MFMA 32x32x16_f16 layout (verified R2):
//   A: row=l&31, k=(l>>5)*8+j ; B: col=l&31, k=(l>>5)*8+j
//   C: col=l&31, row=(i&3)+8*(i>>2)+4*(l>>5)
// ---------------------------------------------------------------------------
__global__ __launch_bounds__(256) void proj_mfma(
    const float* __restrict__ x, const float* __restrict__ sl,
    const f16* __restrict__ wh,
    const float* __restrict__ bq, const float* __restrict__ bk,
    f16* __restrict__ qh, f16* __restrict__ k2h)
{
    __shared__ __align__(16) f16 xs[64 * D_];   // 32 KB
    __shared__ float ksc[64];
    const int b = blockIdx.y, t0 = blockIdx.x * 64;
    const int tid = threadIdx.x;
    const int wv = tid >> 6, l = tid & 63, lo = l & 31, hi = l >> 5;

    #pragma unroll
    for (int i = 0; i < 8; ++i) {
        const int f = i * 256 + tid;
        const int r = f >> 5, j = f & 31;
        const float* src = x + ((size_t)b * T_ + t0 + r) * D_ + j * 8;
        const float4 a0 = *(const float4*)src;
        const float4 a1 = *(const float4*)(src + 4);
        f16x8 h;
        h[0] = (f16)a0.x; h[1] = (f16)a0.y; h[2] = (f16)a0.z; h[3] = (f16)a0.w;
        h[4] = (f16)a1.x; h[5] = (f16)a1.y; h[6] = (f16)a1.z; h[7] = (f16)a1.w;
        *(f16x8*)(xs + r * D_ + ((j ^ (r & 31)) << 3)) = h;
    }
    if (tid < 64) {
        float s = sl[(size_t)b * T_ + t0 + tid];
        s = fminf(fmaxf(s, 0.f), 1.f);
        ksc[tid] = 0.125f * (1.f + s * s) * LOG2E;
    }
    __syncthreads();

    const int r0 = (wv & 1) * 32, c0 = (wv >> 1) * 64;
    f32x16 acc0, acc1;
    #pragma unroll
    for (int i = 0; i < 16; ++i) { acc0[i] = 0.f; acc1[i] = 0.f; }

    const int r = r0 + lo;
    const f16* wrow0 = wh + (size_t)(c0 + lo) * D_ + hi * 8;
    const f16* wrow1 = wh + (size_t)(c0 + 32 + lo) * D_ + hi * 8;
    #pragma unroll
    for (int ks = 0; ks < 16; ++ks) {
        const f16x8 a  = *(const f16x8*)(xs + r * D_ + ((((ks << 1) + hi) ^ (r & 31)) << 3));
        const f16x8 b0 = *(const f16x8*)(wrow0 + ks * 16);
        const f16x8 b1 = *(const f16x8*)(wrow1 + ks * 16);
        acc0 = __builtin_amdgcn_mfma_f32_32x32x16_f16(a, b0, acc0, 0, 0, 0);
        acc1 = __builtin_amdgcn_mfma_f32_32x32x16_f16(a, b1, acc1, 0, 0, 0);
    }

    __syncthreads();
    f16* hout = xs;                  // reuse as [64][128]
    {
        const int col0 = c0 + lo, col1 = c0 + 32 + lo;
        const float bias0 = (col0 < 64) ? bq[col0] : bk[col0 - 64];
        const float bias1 = (col1 < 64) ? bq[col1] : bk[col1 - 64];
        #pragma unroll
        for (int i = 0; i < 16; ++i) {
            const int row = r0 + (i & 3) + 8 * (i >> 2) + 4 * hi;
            float v0 = acc0[i] + bias0;
            float v1 = acc1[i] + bias1;
            if (col0 >= 64) v0 *= ksc[row];
            if (col1 >= 64) v1 *= ksc[row];
            hout[row * 128 + col0] = (f16)v0;
            hout[row * 128 + col1] = (f16)v1;
        }
    }
    __syncthreads();
    #pragma unroll
    for (int i = 0; i < 4; ++i) {
        const int f = i * 256 + tid;
        const int rr = f >> 4, j = f & 15;
        const f16x8 v = *(const f16x8*)(hout + rr * 128 + j * 8);
        if (j < 8) *(f16x8*)(qh  + ((size_t)b * T_ + t0 + rr) * QK_ + j * 8) = v;
        else       *(f16x8*)(k2h + ((size_t)b * T_ + t0 + rr) * QK_ + (j - 8) * 8) = v;
    }
}

// ---------------------------------------------------------------------------
// Kernel 2 (Z partial): zpart[(b*4+ck)][t] = sum_{s in 512-chunk ck}
//                                            2^(S2[t,s] + maskbias[s])
// grid (16 t-tiles x 4 chunks, B) = 1024 blocks -> 4 blocks/CU, 16 waves/CU.
// ---------------------------------------------------------------------------
__global__ __launch_bounds__(256) void z_part(
    const f16* __restrict__ qh, const f16* __restrict__ k2h,
    const int* __restrict__ mask, float* __restrict__ zpart)
{
    __shared__ __align__(16) f16 kt[2][128 * QK_];   // 2 x 16 KB
    __shared__ float mv[2][128];
    const int b = blockIdx.y;
    const int t0 = (blockIdx.x & 15) * 128;
    const int ck = blockIdx.x >> 4;
    const int sbase = ck * 512;
    const int tid = threadIdx.x;
    const int wv = tid >> 6, l = tid & 63, lo = l & 31, hi = l >> 5;

    const f16* qrow = qh + (size_t)(b * T_ + t0 + wv * 32 + lo) * QK_;
    f16x8 a[4];
    #pragma unroll
    for (int kc = 0; kc < 4; ++kc)
        a[kc] = *(const f16x8*)(qrow + kc * 16 + hi * 8);

    float zp[16];
    #pragma unroll
    for (int i = 0; i < 16; ++i) zp[i] = 0.f;

    auto stage = [&](int s0, int buf) {
        const char* src = (const char*)(k2h + (size_t)(b * T_ + s0) * QK_);
        #pragma unroll
        for (int i = 0; i < 4; ++i) {
            const int o = wv * 4096 + i * 1024 + l * 16;
            const int r = o >> 7, jc = (o >> 4) & 7;
            gload_lds16(src + r * 128 + ((jc ^ (r & 7)) << 4),
                        (char*)kt[buf] + wv * 4096 + i * 1024);
        }
        if (tid < 128) mv[buf][tid] = mask[b * T_ + s0 + tid] ? 0.f : -1e9f;
    };

    stage(sbase, 0);
    __syncthreads();
    int cur = 0;
    #pragma unroll
    for (int it = 0; it < 4; ++it) {
        if (it + 1 < 4) stage(sbase + (it + 1) * 128, cur ^ 1);
        const f16* ktc = kt[cur];
        #pragma unroll
        for (int cg = 0; cg < 4; ++cg) {
            const int srow = cg * 32 + lo;
            const float mb = mv[cur][srow];
            f32x16 c;
            #pragma unroll
            for (int i = 0; i < 16; ++i) c[i] = mb;
            #pragma unroll
            for (int kc = 0; kc < 4; ++kc) {
                const int jcc = (kc * 2 + hi) ^ (srow & 7);
                const f16x8 bf = *(const f16x8*)((const char*)ktc + srow * 128 + (jcc << 4));
                c = __builtin_amdgcn_mfma_f32_32x32x16_f16(a[kc], bf, c, 0, 0, 0);
            }
            #pragma unroll
            for (int i = 0; i < 16; ++i) zp[i] += fexp2(c[i]);
        }
        __syncthreads();
        cur ^= 1;
    }

    #pragma unroll
    for (int off = 1; off <= 16; off <<= 1)
        #pragma unroll
        for (int i = 0; i < 16; ++i) zp[i] += __shfl_xor(zp[i], off);

    if (lo == 0) {
        #pragma unroll
        for (int i = 0; i < 16; ++i) {
            const int row = (i & 3) + 8 * (i >> 2) + 4 * hi;
            zpart[(size_t)(b * 4 + ck) * T_ + t0 + wv * 32 + row] = zp[i];
        }
    }
}

// ---------------------------------------------------------------------------
// Kernel 3 (W partial): wpart[(b*4+tc)][s] = sum_{t in 512-chunk tc}
//                       2^(S2[t,s] + lz[t]),  lz[t] = -log2(sum_c zpart[c][t])
// z-reduction folded into the stage step.
// ---------------------------------------------------------------------------
__global__ __launch_bounds__(256) void w_part(
    const f16* __restrict__ qh, const f16* __restrict__ k2h,
    const float* __restrict__ zpart, float* __restrict__ wpart)
{
    __shared__ __align__(16) f16 qt[2][128 * QK_];
    __shared__ float lz[2][128];
    const int b = blockIdx.y;
    const int s0b = (blockIdx.x & 15) * 128;
    const int tc = blockIdx.x >> 4;
    const int tbase = tc * 512;
    const int tid = threadIdx.x;
    const int wv = tid >> 6, l = tid & 63, lo = l & 31, hi = l >> 5;

    const f16* krow = k2h + (size_t)(b * T_ + s0b + wv * 32 + lo) * QK_;
    f16x8 a[4];
    #pragma unroll
    for (int kc = 0; kc < 4; ++kc)
        a[kc] = *(const f16x8*)(krow + kc * 16 + hi * 8);

    float wp[16];
    #pragma unroll
    for (int i = 0; i < 16; ++i) wp[i] = 0.f;

    auto stage = [&](int t0, int buf) {
        const char* src = (const char*)(qh + (size_t)(b * T_ + t0) * QK_);
        #pragma unroll
        for (int i = 0; i < 4; ++i) {
            const int o = wv * 4096 + i * 1024 + l * 16;
            const int r = o >> 7, jc = (o >> 4) & 7;
            gload_lds16(src + r * 128 + ((jc ^ (r & 7)) << 4),
                        (char*)qt[buf] + wv * 4096 + i * 1024);
        }
        if (tid < 128) {
            const float z = zpart[(size_t)(b * 4 + 0) * T_ + t0 + tid]
                          + zpart[(size_t)(b * 4 + 1) * T_ + t0 + tid]
                          + zpart[(size_t)(b * 4 + 2) * T_ + t0 + tid]
                          + zpart[(size_t)(b * 4 + 3) * T_ + t0 + tid];
            lz[buf][tid] = -flog2(z);
        }
    };

    stage(tbase, 0);
    __syncthreads();
    int cur = 0;
    #pragma unroll
    for (int it = 0; it < 4; ++it) {
        if (it + 1 < 4) stage(tbase + (it + 1) * 128, cur ^ 1);
        const f16* qtc = qt[cur];
        #pragma unroll
        for (int cg = 0; cg < 4; ++cg) {
            const int trow = cg * 32 + lo;
            const float bias = lz[cur][trow];
            f32x16 c;
            #pragma unroll
            for (int i = 0; i < 16; ++i) c[i] = bias;
            #pragma unroll
            for (int kc = 0; kc < 4; ++kc) {
                const int jcc = (kc * 2 + hi) ^ (trow & 7);
                const f16x8 bf = *(const f16x8*)((const char*)qtc + trow * 128 + (jcc << 4));
                c = __builtin_amdgcn_mfma_f32_32x32x16_f16(a[kc], bf, c, 0, 0, 0);
            }
            #pragma unroll
            for (int i = 0; i < 16; ++i) wp[i] += fexp2(c[i]);
        }
        __syncthreads();
        cur ^= 1;
    }

    #pragma unroll
    for (int off = 1; off <= 16; off <<= 1)
        #pragma unroll
        for (int i = 0; i < 16; ++i) wp[i] += __shfl_xor(wp[i], off);

    if (lo == 0) {
        #pragma unroll
        for (int i = 0; i < 16; ++i) {
            const int row = (i & 3) + 8 * (i >> 2) + 4 * hi;
            wpart[(size_t)(b * 4 + tc) * T_ + s0b + wv * 32 + row] = wp[i];
        }
    }
}

// ---------------------------------------------------------------------------
// Kernel 4: per 32-row chunk: w[s] = mask[s]/T * sum_c wpart[c][s];
//   ypart[b][ch][d] = sum_s w[s]*x[b,s,d];  swp[b][ch] = sum_s w[s]
// ---------------------------------------------------------------------------
__global__ __launch_bounds__(256) void y_fused(
    const float* __restrict__ x, const float* __restrict__ wpart,
    const int* __restrict__ mask, float* __restrict__ ypart,
    float* __restrict__ swp)
{
    __shared__ float wloc[32];
    const int b  = blockIdx.y;
    const int ch = blockIdx.x;
    const int tid = threadIdx.x;

    if (tid < 32) {
        const int s = ch * 32 + tid;
        float v = wpart[(size_t)(b * 4 + 0) * T_ + s]
                + wpart[(size_t)(b * 4 + 1) * T_ + s]
                + wpart[(size_t)(b * 4 + 2) * T_ + s]
                + wpart[(size_t)(b * 4 + 3) * T_ + s];
        v *= mask[b * T_ + s] ? (1.f / (float)T_) : 0.f;
        wloc[tid] = v;
        float sv = v;
        #pragma unroll
        for (int off = 1; off <= 16; off <<= 1) sv += __shfl_xor(sv, off);
        if (tid == 0) swp[b * 64 + ch] = sv;
    }
    __syncthreads();

    const int d = tid;
    const float* xb = x + ((size_t)b * T_ + ch * 32) * D_;
    float acc = 0.f;
    #pragma unroll 8
    for (int s = 0; s < 32; ++s) acc += wloc[s] * xb[(size_t)s * D_ + d];
    ypart[((size_t)b * 64 + ch) * D_ + d] = acc;
}

// ---------------------------------------------------------------------------
// Kernel 5: out[b][e] = sum_d y[b,d]*Wv[e,d] + bv[e]*sum_s w[b,s]
// ---------------------------------------------------------------------------
__global__ __launch_bounds__(256) void outkernel(
    const float* __restrict__ ypart, const float* __restrict__ swp,
    const float* __restrict__ Wv, const float* __restrict__ bv,
    float* __restrict__ out)
{
    __shared__ __align__(16) float ys[D_];
    __shared__ float sw0;
    const int b   = blockIdx.x;
    const int tid = threadIdx.x;

    float yv = 0.f;
    #pragma unroll
    for (int ch = 0; ch < 64; ++ch) yv += ypart[((size_t)b * 64 + ch) * D_ + tid];
    ys[tid] = yv;

    float s = (tid < 64) ? swp[b * 64 + tid] : 0.f;
    #pragma unroll
    for (int off = 1; off <= 32; off <<= 1) s += __shfl_xor(s, off);
    if (tid == 0) sw0 = s;
    __syncthreads();

    const float sw = sw0;
    const float4* wv4 = (const float4*)(Wv + (size_t)tid * D_);
    const float4* ys4 = (const float4*)ys;
    float o = 0.f;
    for (int i = 0; i < D_ / 4; ++i) {
        const float4 a = wv4[i];
        const float4 y = ys4[i];
        o += a.x * y.x + a.y * y.y + a.z * y.z + a.w * y.w;
    }
    out[(size_t)b * D_ + tid] = o + bv[tid] * sw;
}

// ---------------------------------------------------------------------------
extern "C" void kernel_launch(void* const* d_in, const int* in_sizes, int n_in,
                              void* d_out, int out_size, void* d_ws, size_t ws_size,
                              hipStream_t stream)
{
    const float* x    = (const float*)d_in[0];
    const float* sl   = (const float*)d_in[1];
    const int*   mask = (const int*)d_in[2];
    const float* Wq   = (const float*)d_in[3];
    const float* bq   = (const float*)d_in[4];
    const float* Wk   = (const float*)d_in[5];
    const float* bk   = (const float*)d_in[6];
    const float* Wv   = (const float*)d_in[7];
    const float* bv   = (const float*)d_in[8];
    float* out = (float*)d_out;

    // workspace: qh 4MB | k2h 4MB | wh 64KB | zpart 512KB | wpart 512KB
    //            | swp 4KB | yp 1MB
    f16*   qh    = (f16*)d_ws;
    f16*   k2h   = qh + (size_t)B_ * T_ * QK_;
    f16*   wh    = k2h + (size_t)B_ * T_ * QK_;
    float* zpart = (float*)(wh + 128 * D_);
    float* wpart = zpart + (size_t)B_ * 4 * T_;
    float* swp   = wpart + (size_t)B_ * 4 * T_;
    float* yp    = swp + B_ * 64;

    wconv_kernel<<<dim3(128), 256, 0, stream>>>(Wq, Wk, wh);
    proj_mfma  <<<dim3(T_ / 64, B_), 256, 0, stream>>>(x, sl, wh, bq, bk, qh, k2h);
    z_part     <<<dim3(64, B_), 256, 0, stream>>>(qh, k2h, mask, zpart);
    w_part     <<<dim3(64, B_), 256, 0, stream>>>(qh, k2h, zpart, wpart);
    y_fused    <<<dim3(64, B_), 256, 0, stream>>>(x, wpart, mask, yp, swp);
    outkernel  <<<dim3(B_), 256, 0, stream>>>(yp, swp, Wv, bv, out);
}